// Round 3
// baseline (1920.375 us; speedup 1.0000x reference)
//
#include <hip/hip_runtime.h>

// ODE-GRU recurrence, B=128, L=2048, I=D=64.
// One block per batch (128 blocks, 256 threads = 4 waves).
// R3: 2 broadcast rounds per step (down from 3) via linearity:
//   gh = Whh@h_ode = Whh@h + dt*(M2@t1) + dt*c2,  M2 = Whh@dw2, c2 = Whh@db2
// (M2, c2 precomputed once per launch into d_ws by a prep kernel.)
// Round 1 (read h):  t1 = tanh(dw1@h + db1)  [critical chain, issued first]
//                    gh_h = Whh@h (3 rows/quad, registers — off chain)
// Round 2 (read t1): gh_t = M2@t1, ho_t = dw2@t1 -> gates -> h_new.
// Everything else (DPP quad butterflies, gx tile precompute, LDS-buffered
// output flush) carried from R2.

#define NB    128
#define SEQ   2048
#define DIM   64
#define TILE  32
#define XS    68     // sh_x row stride (floats)
#define GS    200    // sh_gx row stride (floats)

__device__ __forceinline__ float fast_rcp(float x) { return __builtin_amdgcn_rcpf(x); }

__device__ __forceinline__ float sigmoid_f(float v) {
    return fast_rcp(1.0f + __expf(-v));
}
__device__ __forceinline__ float tanh_f(float v) {
    float e = __expf(2.0f * v);
    return fmaf(-2.0f, fast_rcp(e + 1.0f), 1.0f);
}

// Butterfly sum over a lane-quad; every lane of the quad gets the total.
__device__ __forceinline__ float quad_reduce(float v) {
    v += __int_as_float(__builtin_amdgcn_mov_dpp(__float_as_int(v), 0xB1, 0xF, 0xF, true));
    v += __int_as_float(__builtin_amdgcn_mov_dpp(__float_as_int(v), 0x4E, 0xF, 0xF, true));
    return v;
}

__device__ __forceinline__ float dot16(const float4* w, const float4* h) {
    float a0 = 0.f, a1 = 0.f, a2 = 0.f, a3 = 0.f;
    a0 = fmaf(w[0].x, h[0].x, a0); a0 = fmaf(w[0].y, h[0].y, a0);
    a0 = fmaf(w[0].z, h[0].z, a0); a0 = fmaf(w[0].w, h[0].w, a0);
    a1 = fmaf(w[1].x, h[1].x, a1); a1 = fmaf(w[1].y, h[1].y, a1);
    a1 = fmaf(w[1].z, h[1].z, a1); a1 = fmaf(w[1].w, h[1].w, a1);
    a2 = fmaf(w[2].x, h[2].x, a2); a2 = fmaf(w[2].y, h[2].y, a2);
    a2 = fmaf(w[2].z, h[2].z, a2); a2 = fmaf(w[2].w, h[2].w, a2);
    a3 = fmaf(w[3].x, h[3].x, a3); a3 = fmaf(w[3].y, h[3].y, a3);
    a3 = fmaf(w[3].z, h[3].z, a3); a3 = fmaf(w[3].w, h[3].w, a3);
    return (a0 + a1) + (a2 + a3);
}

// ---- prep: M2 = Whh @ dw2 (192x64), c2 = Whh @ db2 (192) ----
__global__ void odegru_prep(const float* __restrict__ w_hh,
                            const float* __restrict__ dw2,
                            const float* __restrict__ db2,
                            float* __restrict__ m2,   // 192*64
                            float* __restrict__ c2)   // 192
{
    const int idx = blockIdx.x * 256 + threadIdx.x;
    if (idx < 192 * 64) {
        const int r = idx >> 6, k = idx & 63;
        float s = 0.f;
#pragma unroll
        for (int j = 0; j < 64; j++) s = fmaf(w_hh[r * 64 + j], dw2[j * 64 + k], s);
        m2[idx] = s;
    }
    if (idx < 192) {
        float s = 0.f;
#pragma unroll
        for (int j = 0; j < 64; j++) s = fmaf(w_hh[idx * 64 + j], db2[j], s);
        c2[idx] = s;
    }
}

__global__ __launch_bounds__(256, 1)
void odegru_fused(const float* __restrict__ x,        // (B,L,I)
                  const float* __restrict__ tds,      // (B,L)
                  const int*   __restrict__ seq_lens, // (B)
                  const float* __restrict__ h0,       // (D)
                  const float* __restrict__ w_ih,     // (3D,I)
                  const float* __restrict__ w_hh,     // (3D,D)
                  const float* __restrict__ b_ih,     // (3D)
                  const float* __restrict__ b_hh,     // (3D)
                  const float* __restrict__ dw1,      // (D,D)
                  const float* __restrict__ db1,      // (D)
                  const float* __restrict__ dw2,      // (D,D)
                  const float* __restrict__ db2,      // (D)
                  const float* __restrict__ m2,       // (3D,D) = Whh@dw2
                  const float* __restrict__ c2,       // (3D)   = Whh@db2
                  float* __restrict__ out)            // (B,L,D) ++ (B,D)
{
    const int b   = blockIdx.x;
    const int tid = threadIdx.x;
    const int q   = tid >> 2;   // quad 0..63: owns output element q
    const int p   = tid & 3;    // lane in quad: K-chunk [16p, 16p+16)
    const int seqlen = seq_lens[b];

    __shared__ float sh_h [DIM];
    __shared__ float sh_t1[DIM];
    __shared__ float sh_x [TILE][XS];
    __shared__ float sh_gx[TILE][GS];
    __shared__ float sh_dt[TILE];
    __shared__ float sh_out[TILE][DIM];

    // ---- persistent weights -> registers: 128 floats/thread ----
    // wa: dw1 row q        | wb: dw2 row q
    // wh[r]: w_hh row 64r+q | wm[r]: M2 row 64r+q      (k-chunk p of each)
    float4 wa[4], wb[4], wh[3][4], wm[3][4];
    {
        const float4* dw1v = (const float4*)dw1;
        const float4* dw2v = (const float4*)dw2;
        const float4* whhv = (const float4*)w_hh;
        const float4* m2v  = (const float4*)m2;
        const int base = q * 16 + p * 4;
#pragma unroll
        for (int i = 0; i < 4; i++) wa[i] = dw1v[base + i];
#pragma unroll
        for (int i = 0; i < 4; i++) wb[i] = dw2v[base + i];
#pragma unroll
        for (int r = 0; r < 3; r++) {
            const int rb = (64 * r + q) * 16 + p * 4;
#pragma unroll
            for (int i = 0; i < 4; i++) { wh[r][i] = whhv[rb + i]; wm[r][i] = m2v[rb + i]; }
        }
    }
    const float rdb1 = db1[q], rdb2 = db2[q];
    const float rbh0 = b_hh[q], rbh1 = b_hh[DIM + q], rbh2 = b_hh[2 * DIM + q];
    const float rbx0 = b_ih[q], rbx1 = b_ih[DIM + q], rbx2 = b_ih[2 * DIM + q];
    const float rc0  = c2[q],  rc1  = c2[DIM + q],  rc2  = c2[2 * DIM + q];

    if (tid < DIM) sh_h[tid] = h0[tid];

    const float* xb  = x   + (size_t)b * SEQ * DIM;
    const float* tdb = tds + (size_t)b * SEQ;
    float* outb = out + (size_t)b * SEQ * DIM;
    float* finb = out + (size_t)NB * SEQ * DIM + (size_t)b * DIM;

    const float4* wihv = (const float4*)w_ih;

    for (int t0 = 0; t0 < SEQ; t0 += TILE) {
        // ---- stage x tile (masked) + dt tile (masked) ----
        {
            const float4* src = (const float4*)(xb + (size_t)t0 * DIM);
#pragma unroll
            for (int i = tid; i < TILE * 16; i += 256) {
                const int ts = i >> 4, j = i & 15;
                float4 v = src[i];
                if (t0 + ts >= seqlen) v = make_float4(0.f, 0.f, 0.f, 0.f);
                *(float4*)&sh_x[ts][4 * j] = v;
            }
            if (tid < TILE) {
                const int t = t0 + tid;
                sh_dt[tid] = (t < seqlen) ? tdb[t] : 0.0f;
            }
        }
        __syncthreads();

        // ---- gx tile: gx[ts][{q,64+q,128+q}] = w_ih rows @ x_ts + b_ih ----
        {
            float4 wi0[4], wi1[4], wi2[4];
            const int c = p * 4;
#pragma unroll
            for (int i = 0; i < 4; i++) {
                wi0[i] = wihv[(q)           * 16 + c + i];
                wi1[i] = wihv[(DIM + q)     * 16 + c + i];
                wi2[i] = wihv[(2 * DIM + q) * 16 + c + i];
            }
#pragma unroll 4
            for (int ts = 0; ts < TILE; ts++) {
                const float4* xv = (const float4*)&sh_x[ts][0];
                float4 x4[4] = { xv[c], xv[c + 1], xv[c + 2], xv[c + 3] };
                float A0 = quad_reduce(dot16(wi0, x4));
                float A1 = quad_reduce(dot16(wi1, x4));
                float A2 = quad_reduce(dot16(wi2, x4));
                if (p == 0) {
                    sh_gx[ts][q]           = A0 + rbx0;
                    sh_gx[ts][DIM + q]     = A1 + rbx1;
                    sh_gx[ts][2 * DIM + q] = A2 + rbx2;
                }
            }
        }
        __syncthreads();

#pragma unroll 1
        for (int ts = 0; ts < TILE; ts++) {
            const int t = t0 + ts;

            // ---- prefetch (independent LDS reads; hide under round 1) ----
            const float gx0 = sh_gx[ts][q];
            const float gx1 = sh_gx[ts][DIM + q];
            const float gx2 = sh_gx[ts][2 * DIM + q];
            const float dtv = sh_dt[ts];
            const float hq  = sh_h[q];

            // ---- Round 1 (read h): t1 chain first, then gh_h rows ----
            float g0, g1, g2;
            {
                const float4* hv = (const float4*)sh_h;
                float4 h4[4] = { hv[p*4], hv[p*4+1], hv[p*4+2], hv[p*4+3] };
                // critical chain: u -> tanh -> LDS write
                float u = quad_reduce(dot16(wa, h4));
                if (p == 0) sh_t1[q] = tanh_f(u + rdb1);
                // off-chain: gh_h = Whh@h rows {q,64+q,128+q}, kept in regs
                g0 = quad_reduce(dot16(wh[0], h4));
                g1 = quad_reduce(dot16(wh[1], h4));
                g2 = quad_reduce(dot16(wh[2], h4));
            }
            __syncthreads();

            // ---- Round 2 (read t1): gh_t = M2@t1, ho_t = dw2@t1, gates ----
            {
                const float4* tv = (const float4*)sh_t1;
                float4 t4[4] = { tv[p*4], tv[p*4+1], tv[p*4+2], tv[p*4+3] };
                float m0  = quad_reduce(dot16(wm[0], t4));
                float m1  = quad_reduce(dot16(wm[1], t4));
                float m2d = quad_reduce(dot16(wm[2], t4));
                float hot = quad_reduce(dot16(wb,    t4));
                const float ghr = fmaf(dtv, m0  + rc0, g0) + rbh0;
                const float ghz = fmaf(dtv, m1  + rc1, g1) + rbh1;
                const float ghn = fmaf(dtv, m2d + rc2, g2) + rbh2;
                const float ho  = fmaf(dtv, hot + rdb2, hq);
                const float rg = sigmoid_f(gx0 + ghr);
                const float zg = sigmoid_f(gx1 + ghz);
                const float ng = tanh_f(fmaf(rg, ghn, gx2));
                const float hn = fmaf(zg, ho - ng, ng);   // (1-z)*n + z*ho
                if (p == 0) {
                    sh_h[q] = hn;
                    sh_out[ts][q] = hn;
                    if (t == seqlen - 1) finb[q] = hn;
                }
            }
            __syncthreads();
        }

        // ---- flush output tile: coalesced float4 stores ----
        {
            float4* dst = (float4*)(outb + (size_t)t0 * DIM);
            const float4* src = (const float4*)(&sh_out[0][0]);
#pragma unroll
            for (int i = tid; i < TILE * DIM / 4; i += 256) dst[i] = src[i];
        }
    }
}

extern "C" void kernel_launch(void* const* d_in, const int* in_sizes, int n_in,
                              void* d_out, int out_size, void* d_ws, size_t ws_size,
                              hipStream_t stream) {
    const float* x    = (const float*)d_in[0];
    const float* tds  = (const float*)d_in[1];
    const int*   sl   = (const int*)  d_in[2];
    const float* h0   = (const float*)d_in[3];
    const float* w_ih = (const float*)d_in[4];
    const float* w_hh = (const float*)d_in[5];
    const float* b_ih = (const float*)d_in[6];
    const float* b_hh = (const float*)d_in[7];
    const float* dw1  = (const float*)d_in[8];
    const float* db1  = (const float*)d_in[9];
    const float* dw2  = (const float*)d_in[10];
    const float* db2  = (const float*)d_in[11];
    float* out = (float*)d_out;

    float* m2 = (float*)d_ws;              // 192*64 floats
    float* c2 = m2 + 192 * 64;             // 192 floats

    odegru_prep<<<dim3(48), dim3(256), 0, stream>>>(w_hh, dw2, db2, m2, c2);
    odegru_fused<<<dim3(NB), dim3(256), 0, stream>>>(
        x, tds, sl, h0, w_ih, w_hh, b_ih, b_hh, dw1, db1, dw2, db2, m2, c2, out);
}

// Round 4
// 1759.473 us; speedup vs baseline: 1.0914x; 1.0914x over previous
//
#include <hip/hip_runtime.h>

// ODE-GRU recurrence, B=128, L=2048, I=D=64.
// One block per batch; R4: 512 threads (8 waves = 2 waves/SIMD for latency
// hiding) + packed-fp32 dots (v_pk_fma_f32 via ext_vector float2).
// Work split per step (quad q<64 = waves 0-3 "lower", 64+q = waves 4-7 "upper"):
//   Round 1 (read h):  lower: u[q]=dw1@h -> t1; G0[q]=Whh_q@h
//                      upper: G1[q]=Whh_{64+q}@h; G2[q]=Whh_{128+q}@h
//   Round 2 (read t1): lower: m0=M2_q@t1, hot=dw2_q@t1 -> r, h_ode (write r,ho)
//                      upper: m1=M2_{64+q}@t1, m2=M2_{128+q}@t1 -> z, ghn
//   Finish (read r,ho): upper: n = tanh(r*ghn+gx2), h_new -> sh_h
// 3 barriers/step (R3 showed barriers cost ~40-90cyc; issue count dominates).
// gh linearity trick (M2=Whh@dw2, c2=Whh@db2 in d_ws) carried from R3.

#define NB    128
#define SEQ   2048
#define DIM   64
#define TILE  32
#define XS    68     // sh_x row stride (floats)
#define GS    200    // sh_gx row stride (floats)

typedef float f32x2 __attribute__((ext_vector_type(2)));

__device__ __forceinline__ float fast_rcp(float x) { return __builtin_amdgcn_rcpf(x); }

__device__ __forceinline__ float sigmoid_f(float v) {
    return fast_rcp(1.0f + __expf(-v));
}
__device__ __forceinline__ float tanh_f(float v) {
    float e = __expf(2.0f * v);
    return fmaf(-2.0f, fast_rcp(e + 1.0f), 1.0f);
}

// Butterfly sum over a lane-quad; every lane of the quad gets the total.
__device__ __forceinline__ float quad_reduce(float v) {
    v += __int_as_float(__builtin_amdgcn_mov_dpp(__float_as_int(v), 0xB1, 0xF, 0xF, true));
    v += __int_as_float(__builtin_amdgcn_mov_dpp(__float_as_int(v), 0x4E, 0xF, 0xF, true));
    return v;
}

// 16-element dot in packed fp32: 8 v_pk_fma_f32 + 1 pk_add + 1 add.
__device__ __forceinline__ float dot16p(const float4* w, const float4* h) {
    f32x2 a; a.x = 0.f; a.y = 0.f;
    f32x2 b; b.x = 0.f; b.y = 0.f;
#pragma unroll
    for (int i = 0; i < 4; i++) {
        f32x2 wlo; wlo.x = w[i].x; wlo.y = w[i].y;
        f32x2 whi; whi.x = w[i].z; whi.y = w[i].w;
        f32x2 hlo; hlo.x = h[i].x; hlo.y = h[i].y;
        f32x2 hhi; hhi.x = h[i].z; hhi.y = h[i].w;
        a = __builtin_elementwise_fma(wlo, hlo, a);
        b = __builtin_elementwise_fma(whi, hhi, b);
    }
    f32x2 s = a + b;
    return s.x + s.y;
}

// ---- prep: M2 = Whh @ dw2 (192x64), c2 = Whh @ db2 (192) ----
__global__ void odegru_prep(const float* __restrict__ w_hh,
                            const float* __restrict__ dw2,
                            const float* __restrict__ db2,
                            float* __restrict__ m2,   // 192*64
                            float* __restrict__ c2)   // 192
{
    const int idx = blockIdx.x * 256 + threadIdx.x;
    if (idx < 192 * 64) {
        const int r = idx >> 6, k = idx & 63;
        float s = 0.f;
#pragma unroll
        for (int j = 0; j < 64; j++) s = fmaf(w_hh[r * 64 + j], dw2[j * 64 + k], s);
        m2[idx] = s;
    }
    if (idx < 192) {
        float s = 0.f;
#pragma unroll
        for (int j = 0; j < 64; j++) s = fmaf(w_hh[idx * 64 + j], db2[j], s);
        c2[idx] = s;
    }
}

__global__ __launch_bounds__(512, 2)
void odegru_fused(const float* __restrict__ x,        // (B,L,I)
                  const float* __restrict__ tds,      // (B,L)
                  const int*   __restrict__ seq_lens, // (B)
                  const float* __restrict__ h0,       // (D)
                  const float* __restrict__ w_ih,     // (3D,I)
                  const float* __restrict__ w_hh,     // (3D,D)
                  const float* __restrict__ b_ih,     // (3D)
                  const float* __restrict__ b_hh,     // (3D)
                  const float* __restrict__ dw1,      // (D,D)
                  const float* __restrict__ db1,      // (D)
                  const float* __restrict__ dw2,      // (D,D)
                  const float* __restrict__ db2,      // (D)
                  const float* __restrict__ m2,       // (3D,D) = Whh@dw2
                  const float* __restrict__ c2,       // (3D)   = Whh@db2
                  float* __restrict__ out)            // (B,L,D) ++ (B,D)
{
    const int b   = blockIdx.x;
    const int tid = threadIdx.x;
    const int q   = (tid >> 2) & 63;  // element index 0..63
    const int p   = tid & 3;          // lane in quad: K-chunk [16p,16p+16)
    const bool up = tid >= 256;       // waves 4-7
    const int seqlen = seq_lens[b];

    __shared__ float sh_h [DIM];
    __shared__ float sh_t1[DIM];
    __shared__ float sh_r [DIM];
    __shared__ float sh_ho[DIM];
    __shared__ float sh_x [TILE][XS];
    __shared__ float sh_gx[TILE][GS];
    __shared__ float sh_dt[TILE];
    __shared__ float sh_out[TILE][DIM];

    // ---- persistent weights: 4 dot-rows (64 floats) + 3 gx-rows (48) ----
    float4 wA[4], wB[4], wC[4], wD[4], wi0[4], wi1[4], wi2[4];
    {
        const float4* dw1v = (const float4*)dw1;
        const float4* dw2v = (const float4*)dw2;
        const float4* whhv = (const float4*)w_hh;
        const float4* m2v  = (const float4*)m2;
        const float4* wihv = (const float4*)w_ih;
        const int c = p * 4;
        if (!up) {
#pragma unroll
            for (int i = 0; i < 4; i++) {
                wA[i] = dw1v[q * 16 + c + i];           // dw1 row q
                wB[i] = whhv[q * 16 + c + i];           // Whh row q
                wC[i] = m2v [q * 16 + c + i];           // M2  row q
                wD[i] = dw2v[q * 16 + c + i];           // dw2 row q
            }
        } else {
#pragma unroll
            for (int i = 0; i < 4; i++) {
                wA[i] = whhv[(64  + q) * 16 + c + i];   // Whh row 64+q
                wB[i] = whhv[(128 + q) * 16 + c + i];   // Whh row 128+q
                wC[i] = m2v [(64  + q) * 16 + c + i];   // M2  row 64+q
                wD[i] = m2v [(128 + q) * 16 + c + i];   // M2  row 128+q
            }
        }
#pragma unroll
        for (int i = 0; i < 4; i++) {
            wi0[i] = wihv[(q)       * 16 + c + i];
            wi1[i] = wihv[(64 + q)  * 16 + c + i];
            wi2[i] = wihv[(128 + q) * 16 + c + i];
        }
    }
    // biases (role depends on half)
    float kd1 = 0.f, kbh = 0.f, kc = 0.f, kdb2 = 0.f, kbh2 = 0.f, kc2 = 0.f;
    if (!up) { kd1 = db1[q]; kbh = b_hh[q];      kc = c2[q];      kdb2 = db2[q]; }
    else     {               kbh = b_hh[64 + q]; kc = c2[64 + q];
               kbh2 = b_hh[128 + q]; kc2 = c2[128 + q]; }
    const float rbx0 = b_ih[q], rbx1 = b_ih[64 + q], rbx2 = b_ih[128 + q];

    if (tid < DIM) sh_h[tid] = h0[tid];

    const float* xb  = x   + (size_t)b * SEQ * DIM;
    const float* tdb = tds + (size_t)b * SEQ;
    float* outb = out + (size_t)b * SEQ * DIM;
    float* finb = out + (size_t)NB * SEQ * DIM + (size_t)b * DIM;

    for (int t0 = 0; t0 < SEQ; t0 += TILE) {
        // ---- stage x tile (masked) + dt tile (masked); 512 f4 = 1/thread ----
        {
            const float4* src = (const float4*)(xb + (size_t)t0 * DIM);
            const int ts0 = tid >> 4, j = tid & 15;
            float4 v = src[tid];
            if (t0 + ts0 >= seqlen) v = make_float4(0.f, 0.f, 0.f, 0.f);
            *(float4*)&sh_x[ts0][4 * j] = v;
            if (tid < TILE) {
                const int t = t0 + tid;
                sh_dt[tid] = (t < seqlen) ? tdb[t] : 0.0f;
            }
        }
        __syncthreads();

        // ---- gx tile: rows {q,64+q,128+q}; lower=even ts, upper=odd ts ----
        {
            const int c = p * 4;
            for (int ts = up ? 1 : 0; ts < TILE; ts += 2) {
                const float4* xv = (const float4*)&sh_x[ts][0];
                float4 x4[4] = { xv[c], xv[c + 1], xv[c + 2], xv[c + 3] };
                float A0 = quad_reduce(dot16p(wi0, x4));
                float A1 = quad_reduce(dot16p(wi1, x4));
                float A2 = quad_reduce(dot16p(wi2, x4));
                if (p == 0) {
                    sh_gx[ts][q]       = A0 + rbx0;
                    sh_gx[ts][64 + q]  = A1 + rbx1;
                    sh_gx[ts][128 + q] = A2 + rbx2;
                }
            }
        }
        __syncthreads();

#pragma unroll 1
        for (int ts = 0; ts < TILE; ts++) {
            const int t = t0 + ts;

            // ---- prefetch (independent LDS reads) ----
            const float dtv = sh_dt[ts];
            float gxa, gxb = 0.f, hq = 0.f;
            if (!up) { gxa = sh_gx[ts][q];       hq  = sh_h[q]; }
            else     { gxa = sh_gx[ts][64 + q];  gxb = sh_gx[ts][128 + q]; }

            // ---- Round 1 (read h): 2 dots/lane ----
            const float4* hv = (const float4*)sh_h;
            float4 h4[4] = { hv[4*p], hv[4*p+1], hv[4*p+2], hv[4*p+3] };
            float sA = quad_reduce(dot16p(wA, h4));
            float sB = quad_reduce(dot16p(wB, h4));
            float G1, G2 = 0.f;
            if (!up) {
                if (p == 0) sh_t1[q] = tanh_f(sA + kd1);
                G1 = sB;                       // G0 = Whh_q @ h
            } else {
                G1 = sA; G2 = sB;              // Whh_{64+q}@h, Whh_{128+q}@h
            }
            __syncthreads();   // A: t1 visible

            // ---- Round 2 (read t1): 2 dots/lane ----
            const float4* tv = (const float4*)sh_t1;
            float4 t4[4] = { tv[4*p], tv[4*p+1], tv[4*p+2], tv[4*p+3] };
            float sC = quad_reduce(dot16p(wC, t4));
            float sD = quad_reduce(dot16p(wD, t4));
            float zv = 0.f, ghn = 0.f;
            if (!up) {
                // r-gate + h_ode
                const float r  = sigmoid_f(gxa + G1 + fmaf(dtv, sC + kc, kbh));
                const float ho = fmaf(dtv, sD + kdb2, hq);
                if (p == 0) { sh_r[q] = r; sh_ho[q] = ho; }
            } else {
                zv  = sigmoid_f(gxa + G1 + fmaf(dtv, sC + kc, kbh));
                ghn = G2 + fmaf(dtv, sD + kc2, kbh2);
            }
            __syncthreads();   // B: r, ho visible

            // ---- Finish (upper): n, h_new ----
            if (up) {
                const float r  = sh_r[q];
                const float ho = sh_ho[q];
                const float n  = tanh_f(fmaf(r, ghn, gxb));
                const float hn = fmaf(zv, ho - n, n);   // (1-z)*n + z*ho
                if (p == 0) {
                    sh_h[q] = hn;
                    sh_out[ts][q] = hn;
                    if (t == seqlen - 1) finb[q] = hn;
                }
            }
            __syncthreads();   // C: h visible
        }

        // ---- flush output tile: 512 float4 = 1/thread ----
        {
            float4* dst = (float4*)(outb + (size_t)t0 * DIM);
            const float4* srcv = (const float4*)(&sh_out[0][0]);
            dst[tid] = srcv[tid];
        }
    }
}

extern "C" void kernel_launch(void* const* d_in, const int* in_sizes, int n_in,
                              void* d_out, int out_size, void* d_ws, size_t ws_size,
                              hipStream_t stream) {
    const float* x    = (const float*)d_in[0];
    const float* tds  = (const float*)d_in[1];
    const int*   sl   = (const int*)  d_in[2];
    const float* h0   = (const float*)d_in[3];
    const float* w_ih = (const float*)d_in[4];
    const float* w_hh = (const float*)d_in[5];
    const float* b_ih = (const float*)d_in[6];
    const float* b_hh = (const float*)d_in[7];
    const float* dw1  = (const float*)d_in[8];
    const float* db1  = (const float*)d_in[9];
    const float* dw2  = (const float*)d_in[10];
    const float* db2  = (const float*)d_in[11];
    float* out = (float*)d_out;

    float* m2 = (float*)d_ws;              // 192*64 floats
    float* c2 = m2 + 192 * 64;             // 192 floats

    odegru_prep<<<dim3(48), dim3(256), 0, stream>>>(w_hh, dw2, db2, m2, c2);
    odegru_fused<<<dim3(NB), dim3(512), 0, stream>>>(
        x, tds, sl, h0, w_ih, w_hh, b_ih, b_hh, dw1, db1, dw2, db2, m2, c2, out);
}

// Round 5
// 1680.013 us; speedup vs baseline: 1.1431x; 1.0473x over previous
//
#include <hip/hip_runtime.h>

// ODE-GRU recurrence, B=128, L=2048, I=D=64.
// One block per batch, 512 threads (8 waves, 2/SIMD).
// R5: 2 barriers/step (algebraic minimum) via octet-per-element layout.
//   Element q owned by lanes 8q..8q+7 (quad A = lanes 8q+0..3, quad B = +4..7).
//   Round 1 (read h):  A: u=dw1_q@h -> t1 write; G1=Whh_{64+q}@h
//                      B: G0=Whh_q@h; G2=Whh_{128+q}@h
//   Round 2 (read t1): A: m1=M2_{64+q}@t1, hot=dw2_q@t1 -> z, h_ode
//                      B: m0=M2_q@t1, m2=M2_{128+q}@t1 -> r, ghn, n=tanh(r*ghn+gx2)
//   n moved B->A with one DPP row_half_mirror (0x141) — no LDS, no barrier;
//   A computes h_new, writes sh_h[q]. sh_r/sh_ho eliminated.
// Carried: gh linearity (M2=Whh@dw2, c2=Whh@db2 prep into d_ws), packed-fp32
// dots, DPP quad butterflies, gx tile precompute, LDS-buffered output flush.

#define NB    128
#define SEQ   2048
#define DIM   64
#define TILE  32
#define XS    68     // sh_x row stride (floats)
#define GS    200    // sh_gx row stride (floats)

typedef float f32x2 __attribute__((ext_vector_type(2)));

__device__ __forceinline__ float fast_rcp(float x) { return __builtin_amdgcn_rcpf(x); }

__device__ __forceinline__ float sigmoid_f(float v) {
    return fast_rcp(1.0f + __expf(-v));
}
__device__ __forceinline__ float tanh_f(float v) {
    float e = __expf(2.0f * v);
    return fmaf(-2.0f, fast_rcp(e + 1.0f), 1.0f);
}

// Butterfly sum over a lane-quad; every lane of the quad gets the total.
__device__ __forceinline__ float quad_reduce(float v) {
    v += __int_as_float(__builtin_amdgcn_mov_dpp(__float_as_int(v), 0xB1, 0xF, 0xF, true));
    v += __int_as_float(__builtin_amdgcn_mov_dpp(__float_as_int(v), 0x4E, 0xF, 0xF, true));
    return v;
}

// Swap values between the two quads of each 8-lane octet (row_half_mirror).
__device__ __forceinline__ float octet_swap(float v) {
    return __int_as_float(__builtin_amdgcn_mov_dpp(__float_as_int(v), 0x141, 0xF, 0xF, true));
}

// 16-element dot in packed fp32: 8 v_pk_fma_f32 + pk_add + add.
__device__ __forceinline__ float dot16p(const float4* w, const float4* h) {
    f32x2 a; a.x = 0.f; a.y = 0.f;
    f32x2 b; b.x = 0.f; b.y = 0.f;
#pragma unroll
    for (int i = 0; i < 4; i++) {
        f32x2 wlo; wlo.x = w[i].x; wlo.y = w[i].y;
        f32x2 whi; whi.x = w[i].z; whi.y = w[i].w;
        f32x2 hlo; hlo.x = h[i].x; hlo.y = h[i].y;
        f32x2 hhi; hhi.x = h[i].z; hhi.y = h[i].w;
        a = __builtin_elementwise_fma(wlo, hlo, a);
        b = __builtin_elementwise_fma(whi, hhi, b);
    }
    f32x2 s = a + b;
    return s.x + s.y;
}

// ---- prep: M2 = Whh @ dw2 (192x64), c2 = Whh @ db2 (192) ----
__global__ void odegru_prep(const float* __restrict__ w_hh,
                            const float* __restrict__ dw2,
                            const float* __restrict__ db2,
                            float* __restrict__ m2,   // 192*64
                            float* __restrict__ c2)   // 192
{
    const int idx = blockIdx.x * 256 + threadIdx.x;
    if (idx < 192 * 64) {
        const int r = idx >> 6, k = idx & 63;
        float s = 0.f;
#pragma unroll
        for (int j = 0; j < 64; j++) s = fmaf(w_hh[r * 64 + j], dw2[j * 64 + k], s);
        m2[idx] = s;
    }
    if (idx < 192) {
        float s = 0.f;
#pragma unroll
        for (int j = 0; j < 64; j++) s = fmaf(w_hh[idx * 64 + j], db2[j], s);
        c2[idx] = s;
    }
}

__global__ __launch_bounds__(512, 2)
void odegru_fused(const float* __restrict__ x,        // (B,L,I)
                  const float* __restrict__ tds,      // (B,L)
                  const int*   __restrict__ seq_lens, // (B)
                  const float* __restrict__ h0,       // (D)
                  const float* __restrict__ w_ih,     // (3D,I)
                  const float* __restrict__ w_hh,     // (3D,D)
                  const float* __restrict__ b_ih,     // (3D)
                  const float* __restrict__ b_hh,     // (3D)
                  const float* __restrict__ dw1,      // (D,D)
                  const float* __restrict__ db1,      // (D)
                  const float* __restrict__ dw2,      // (D,D)
                  const float* __restrict__ db2,      // (D)
                  const float* __restrict__ m2,       // (3D,D) = Whh@dw2
                  const float* __restrict__ c2,       // (3D)   = Whh@db2
                  float* __restrict__ out)            // (B,L,D) ++ (B,D)
{
    const int b   = blockIdx.x;
    const int tid = threadIdx.x;
    const int q8  = tid >> 3;         // octet = element 0..63
    const int p   = tid & 3;          // K-chunk within quad: [16p,16p+16)
    const bool qb = (tid & 4) != 0;   // quad B of the octet
    const int seqlen = seq_lens[b];

    __shared__ float sh_h [DIM];
    __shared__ float sh_t1[DIM];
    __shared__ float sh_x [TILE][XS];
    __shared__ float sh_gx[TILE][GS];
    __shared__ float sh_dt[TILE];
    __shared__ float sh_out[TILE][DIM];

    // ---- persistent weights: 4 dot-rows (64 floats) + 3 gx-rows (48) ----
    float4 wA[4], wB[4], wC[4], wD[4], wi0[4], wi1[4], wi2[4];
    {
        const float4* dw1v = (const float4*)dw1;
        const float4* dw2v = (const float4*)dw2;
        const float4* whhv = (const float4*)w_hh;
        const float4* m2v  = (const float4*)m2;
        const float4* wihv = (const float4*)w_ih;
        const int c = p * 4;
        if (!qb) {
#pragma unroll
            for (int i = 0; i < 4; i++) {
                wA[i] = dw1v[q8 * 16 + c + i];            // u    = dw1_q @ h
                wB[i] = whhv[(64 + q8) * 16 + c + i];     // G1   = Whh_{64+q} @ h
                wC[i] = m2v [(64 + q8) * 16 + c + i];     // m1   = M2_{64+q} @ t1
                wD[i] = dw2v[q8 * 16 + c + i];            // hot  = dw2_q @ t1
            }
        } else {
#pragma unroll
            for (int i = 0; i < 4; i++) {
                wA[i] = whhv[q8 * 16 + c + i];            // G0   = Whh_q @ h
                wB[i] = whhv[(128 + q8) * 16 + c + i];    // G2   = Whh_{128+q} @ h
                wC[i] = m2v [q8 * 16 + c + i];            // m0   = M2_q @ t1
                wD[i] = m2v [(128 + q8) * 16 + c + i];    // m2   = M2_{128+q} @ t1
            }
        }
        // gx precompute rows (R4 layout: quad qg = (tid>>2)&63)
        const int qg = (tid >> 2) & 63;
#pragma unroll
        for (int i = 0; i < 4; i++) {
            wi0[i] = wihv[(qg)       * 16 + c + i];
            wi1[i] = wihv[(64 + qg)  * 16 + c + i];
            wi2[i] = wihv[(128 + qg) * 16 + c + i];
        }
    }
    // biases: quad A: {db1_q, bh1, c1, db2_q}; quad B: {bh0, c0, bh2, c2n}
    float fA, fB, fC, fD;
    if (!qb) { fA = db1[q8];      fB = b_hh[64 + q8];  fC = c2[64 + q8];   fD = db2[q8]; }
    else     { fA = b_hh[q8];     fB = c2[q8];         fC = b_hh[128 + q8]; fD = c2[128 + q8]; }
    const int qg = (tid >> 2) & 63;
    const float rbx0 = b_ih[qg], rbx1 = b_ih[64 + qg], rbx2 = b_ih[128 + qg];

    if (tid < DIM) sh_h[tid] = h0[tid];

    const float* xb  = x   + (size_t)b * SEQ * DIM;
    const float* tdb = tds + (size_t)b * SEQ;
    float* outb = out + (size_t)b * SEQ * DIM;
    float* finb = out + (size_t)NB * SEQ * DIM + (size_t)b * DIM;

    for (int t0 = 0; t0 < SEQ; t0 += TILE) {
        // ---- stage x tile (masked) + dt tile (masked); 512 f4 = 1/thread ----
        {
            const float4* src = (const float4*)(xb + (size_t)t0 * DIM);
            const int ts0 = tid >> 4, j = tid & 15;
            float4 v = src[tid];
            if (t0 + ts0 >= seqlen) v = make_float4(0.f, 0.f, 0.f, 0.f);
            *(float4*)&sh_x[ts0][4 * j] = v;
            if (tid < TILE) {
                const int t = t0 + tid;
                sh_dt[tid] = (t < seqlen) ? tdb[t] : 0.0f;
            }
        }
        __syncthreads();

        // ---- gx tile: rows {qg,64+qg,128+qg}; lower half even ts, upper odd ----
        {
            const int c = p * 4;
            for (int ts = (tid >= 256) ? 1 : 0; ts < TILE; ts += 2) {
                const float4* xv = (const float4*)&sh_x[ts][0];
                float4 x4[4] = { xv[c], xv[c + 1], xv[c + 2], xv[c + 3] };
                float A0 = quad_reduce(dot16p(wi0, x4));
                float A1 = quad_reduce(dot16p(wi1, x4));
                float A2 = quad_reduce(dot16p(wi2, x4));
                if (p == 0) {
                    sh_gx[ts][qg]       = A0 + rbx0;
                    sh_gx[ts][64 + qg]  = A1 + rbx1;
                    sh_gx[ts][128 + qg] = A2 + rbx2;
                }
            }
        }
        __syncthreads();

#pragma unroll 1
        for (int ts = 0; ts < TILE; ts++) {
            const int t = t0 + ts;

            // ---- prefetch (independent LDS reads) ----
            const float dtv = sh_dt[ts];
            float gA, gB = 0.f, hq = 0.f;
            if (!qb) { gA = sh_gx[ts][64 + q8]; hq = sh_h[q8]; }       // gx1
            else     { gA = sh_gx[ts][q8];      gB = sh_gx[ts][128 + q8]; } // gx0, gx2

            // ---- Round 1 (read h): 2 dots/lane ----
            const float4* hv = (const float4*)sh_h;
            float4 h4[4] = { hv[4*p], hv[4*p+1], hv[4*p+2], hv[4*p+3] };
            const float sA = quad_reduce(dot16p(wA, h4));  // A: u   | B: G0
            const float sB = quad_reduce(dot16p(wB, h4));  // A: G1  | B: G2
            if (!qb) {
                const float t1v = tanh_f(sA + fA);
                if (p == 0) sh_t1[q8] = t1v;
            }
            __syncthreads();   // t1 visible

            // ---- Round 2 (read t1): 2 dots/lane + finish ----
            const float4* tv = (const float4*)sh_t1;
            float4 t4[4] = { tv[4*p], tv[4*p+1], tv[4*p+2], tv[4*p+3] };
            const float sC = quad_reduce(dot16p(wC, t4));  // A: m1  | B: m0
            const float sD = quad_reduce(dot16p(wD, t4));  // A: hot | B: m2
            float val, z = 0.f, ho = 0.f;
            if (!qb) {
                z   = sigmoid_f(gA + sB + fmaf(dtv, sC + fC, fB));     // z-gate
                ho  = fmaf(dtv, sD + fD, hq);                          // h_ode
                val = 0.f;
            } else {
                const float r   = sigmoid_f(gA + sA + fmaf(dtv, sC + fB, fA));
                const float ghn = sB + fmaf(dtv, sD + fD, fC);
                val = tanh_f(fmaf(r, ghn, gB));                        // n
            }
            const float n = octet_swap(val);   // quad A receives n from quad B
            if (!qb) {
                const float hn = fmaf(z, ho - n, n);   // (1-z)*n + z*ho
                if (p == 0) {
                    sh_h[q8] = hn;
                    sh_out[ts][q8] = hn;
                    if (t == seqlen - 1) finb[q8] = hn;
                }
            }
            __syncthreads();   // h visible
        }

        // ---- flush output tile: 512 float4 = 1/thread ----
        {
            float4* dst = (float4*)(outb + (size_t)t0 * DIM);
            const float4* srcv = (const float4*)(&sh_out[0][0]);
            dst[tid] = srcv[tid];
        }
    }
}

extern "C" void kernel_launch(void* const* d_in, const int* in_sizes, int n_in,
                              void* d_out, int out_size, void* d_ws, size_t ws_size,
                              hipStream_t stream) {
    const float* x    = (const float*)d_in[0];
    const float* tds  = (const float*)d_in[1];
    const int*   sl   = (const int*)  d_in[2];
    const float* h0   = (const float*)d_in[3];
    const float* w_ih = (const float*)d_in[4];
    const float* w_hh = (const float*)d_in[5];
    const float* b_ih = (const float*)d_in[6];
    const float* b_hh = (const float*)d_in[7];
    const float* dw1  = (const float*)d_in[8];
    const float* db1  = (const float*)d_in[9];
    const float* dw2  = (const float*)d_in[10];
    const float* db2  = (const float*)d_in[11];
    float* out = (float*)d_out;

    float* m2 = (float*)d_ws;              // 192*64 floats
    float* c2 = m2 + 192 * 64;             // 192 floats

    odegru_prep<<<dim3(48), dim3(256), 0, stream>>>(w_hh, dw2, db2, m2, c2);
    odegru_fused<<<dim3(NB), dim3(512), 0, stream>>>(
        x, tds, sl, h0, w_ih, w_hh, b_ih, b_hh, dw1, db1, dw2, db2, m2, c2, out);
}